// Round 1
// baseline (1324.116 us; speedup 1.0000x reference)
//
#include <hip/hip_runtime.h>

// Problem constants
#define VSZ   50257
#define VPAD  50304   // 393 * 128, zero-padded rows for the head GEMM
#define D_    768
#define H_    128
#define BL_   2048    // B*L = 2*1024
#define LSEQ  1024

typedef __bf16 bf16x8 __attribute__((ext_vector_type(8)));
typedef float  f32x4  __attribute__((ext_vector_type(4)));

__device__ __forceinline__ unsigned short f32_to_bf16(float f) {
  unsigned int u = __float_as_uint(f);
  u += 0x7fffu + ((u >> 16) & 1u);   // round-to-nearest-even
  return (unsigned short)(u >> 16);
}

__device__ __forceinline__ void gload_lds16(const void* g, void* l) {
  __builtin_amdgcn_global_load_lds((const __attribute__((address_space(1))) void*)g,
                                   (__attribute__((address_space(3))) void*)l,
                                   16, 0, 0);
}

// ---------------- K0: embed fp32 -> bf16, padded to VPAD rows ----------------
__global__ __launch_bounds__(256) void convert_embed(const float* __restrict__ embed,
                                                     unsigned short* __restrict__ Eb) {
  int idx = blockIdx.x * 256 + threadIdx.x;   // float4 index, VPAD*192 total
  int row = idx / 192;
  ushort4 o;
  if (row < VSZ) {
    float4 f = ((const float4*)embed)[idx];
    o.x = f32_to_bf16(f.x); o.y = f32_to_bf16(f.y);
    o.z = f32_to_bf16(f.z); o.w = f32_to_bf16(f.w);
  } else {
    o = make_ushort4(0, 0, 0, 0);
  }
  ((ushort4*)Eb)[idx] = o;
}

// ---------------- K1: token gather -> h [2048][768] ----------------
__global__ __launch_bounds__(256) void gather_embed(const int* __restrict__ x,
                                                    const float* __restrict__ embed,
                                                    float* __restrict__ h) {
  int idx = blockIdx.x * 256 + threadIdx.x;   // 2048*192
  int m = idx / 192, d4 = idx - m * 192;
  int tok = x[m];
  ((float4*)h)[idx] = ((const float4*)embed)[(size_t)tok * 192 + d4];
}

// ---------------- K2: depthwise causal conv (K=4) + SiLU ----------------
__global__ __launch_bounds__(256) void conv_silu(const float* __restrict__ h,
                                                 const float* __restrict__ cw,  // [768][4]
                                                 const float* __restrict__ cb,  // [768]
                                                 float* __restrict__ u) {
  int idx = blockIdx.x * 256 + threadIdx.x;   // 2048*192
  int m = idx / 192, d4 = idx - m * 192;
  int b = m >> 10, l = m & 1023;
  const float4* cw4 = (const float4*)cw;
  float4 w0 = cw4[d4 * 4 + 0], w1 = cw4[d4 * 4 + 1];
  float4 w2 = cw4[d4 * 4 + 2], w3 = cw4[d4 * 4 + 3];
  float4 acc = ((const float4*)cb)[d4];
  #pragma unroll
  for (int j = 0; j < 4; ++j) {
    int lj = l + j - 3;
    if (lj >= 0) {
      float4 xv = ((const float4*)h)[(size_t)((b << 10) + lj) * 192 + d4];
      acc.x += xv.x * (&w0.x)[j];
      acc.y += xv.y * (&w1.x)[j];
      acc.z += xv.z * (&w2.x)[j];
      acc.w += xv.w * (&w3.x)[j];
    }
  }
  acc.x = acc.x / (1.f + expf(-acc.x));
  acc.y = acc.y / (1.f + expf(-acc.y));
  acc.z = acc.z / (1.f + expf(-acc.z));
  acc.w = acc.w / (1.f + expf(-acc.w));
  ((float4*)u)[idx] = acc;
}

// ---------------- K3: pre = u @ [Wd | Win]  -> [2048][256] ----------------
// grid (128, 2); Mtile=16, Ntile=128; thread = 2m x 4n
__global__ __launch_bounds__(256) void gemm_dbu(const float* __restrict__ u,
                                                const float* __restrict__ Wd,
                                                const float* __restrict__ Wi,
                                                float* __restrict__ pre) {
  __shared__ float Au[16 * 33];
  int m0 = blockIdx.x * 16;
  int sel = blockIdx.y;
  const float* W = sel ? Wi : Wd;
  int tid = threadIdx.x;
  int tm = tid & 7, tn = tid >> 3;
  float acc[2][4] = {};
  for (int k0 = 0; k0 < 768; k0 += 32) {
    __syncthreads();
    {
      int e = tid;        int mr = e >> 5, k = e & 31;
      Au[mr * 33 + k] = u[(size_t)(m0 + mr) * 768 + k0 + k];
      e = tid + 256;      mr = e >> 5;     k = e & 31;
      Au[mr * 33 + k] = u[(size_t)(m0 + mr) * 768 + k0 + k];
    }
    __syncthreads();
    #pragma unroll 8
    for (int k = 0; k < 32; ++k) {
      float4 w = *(const float4*)&W[(size_t)(k0 + k) * 128 + tn * 4];
      float a0 = Au[(tm * 2 + 0) * 33 + k];
      float a1 = Au[(tm * 2 + 1) * 33 + k];
      acc[0][0] += a0 * w.x; acc[0][1] += a0 * w.y; acc[0][2] += a0 * w.z; acc[0][3] += a0 * w.w;
      acc[1][0] += a1 * w.x; acc[1][1] += a1 * w.y; acc[1][2] += a1 * w.z; acc[1][3] += a1 * w.w;
    }
  }
  #pragma unroll
  for (int mi = 0; mi < 2; ++mi) {
    float4 o = make_float4(acc[mi][0], acc[mi][1], acc[mi][2], acc[mi][3]);
    *(float4*)&pre[(size_t)(m0 + tm * 2 + mi) * 256 + sel * 128 + tn * 4] = o;
  }
}

// ---------------- scan helpers: decay/inc on the fly ----------------
__device__ __forceinline__ void dz_at(const float* __restrict__ pre, float bdv, float negA,
                                      int m, int hh, float& d, float& z) {
  float pd = pre[(size_t)m * 256 + hh];
  float bu = pre[(size_t)m * 256 + 128 + hh];
  float xx = pd + bdv;
  float delta = (xx > 20.f) ? xx : log1pf(expf(xx));
  d = expf(delta * negA);
  z = delta * bu;
}

// Pass A: per-chunk (P, Q); 32 chunks of 32 steps; 8192 threads
__global__ __launch_bounds__(256) void scan_chunks(const float* __restrict__ pre,
                                                   const float* __restrict__ bd,
                                                   const float* __restrict__ logA,
                                                   float* __restrict__ cP,
                                                   float* __restrict__ cQ) {
  int t = blockIdx.x * 256 + threadIdx.x;
  int hh = t & 127, b = (t >> 7) & 1, c = t >> 8;
  float bdv = bd[hh];
  float negA = -expf(logA[hh]);
  float P = 1.f, Q = 0.f;
  int mbase = b * LSEQ + c * 32;
  for (int s = 0; s < 32; ++s) {
    float d, z;
    dz_at(pre, bdv, negA, mbase + s, hh, d, z);
    Q = d * Q + z;
    P *= d;
  }
  int bh = b * 128 + hh;
  cP[c * 256 + bh] = P;
  cQ[c * 256 + bh] = Q;
}

// Pass B: scan chunk summaries -> chunk-start states
__global__ __launch_bounds__(256) void scan_tops(const float* __restrict__ cP,
                                                 const float* __restrict__ cQ,
                                                 float* __restrict__ sst) {
  int bh = threadIdx.x;
  float s = 0.f;
  for (int c = 0; c < 32; ++c) {
    sst[c * 256 + bh] = s;
    s = cP[c * 256 + bh] * s + cQ[c * 256 + bh];
  }
}

// Pass C: replay with correct start state, write hs [2048][128]
__global__ __launch_bounds__(256) void scan_final(const float* __restrict__ pre,
                                                  const float* __restrict__ bd,
                                                  const float* __restrict__ logA,
                                                  const float* __restrict__ sst,
                                                  float* __restrict__ hsout) {
  int t = blockIdx.x * 256 + threadIdx.x;
  int hh = t & 127, b = (t >> 7) & 1, c = t >> 8;
  float bdv = bd[hh];
  float negA = -expf(logA[hh]);
  int bh = b * 128 + hh;
  float s = sst[c * 256 + bh];
  int mbase = b * LSEQ + c * 32;
  for (int st = 0; st < 32; ++st) {
    float d, z;
    dz_at(pre, bdv, negA, mbase + st, hh, d, z);
    s = d * s + z;
    hsout[(size_t)(mbase + st) * 128 + hh] = s;
  }
}

// ---------------- K6: h += hs @ Wout ; grid (128, 6) ----------------
__global__ __launch_bounds__(256) void gemm_out(const float* __restrict__ hs,
                                                const float* __restrict__ Wout, // [128][768]
                                                float* __restrict__ h) {
  __shared__ float Hs[16 * 129];
  int m0 = blockIdx.x * 16;
  int n0 = blockIdx.y * 128;
  int tid = threadIdx.x;
  int tm = tid & 7, tn = tid >> 3;
  for (int e = tid; e < 2048; e += 256) {
    int mr = e >> 7, k = e & 127;
    Hs[mr * 129 + k] = hs[(size_t)(m0 + mr) * 128 + k];
  }
  __syncthreads();
  float acc[2][4] = {};
  #pragma unroll 4
  for (int k = 0; k < 128; ++k) {
    float4 w = *(const float4*)&Wout[(size_t)k * 768 + n0 + tn * 4];
    float a0 = Hs[(tm * 2 + 0) * 129 + k];
    float a1 = Hs[(tm * 2 + 1) * 129 + k];
    acc[0][0] += a0 * w.x; acc[0][1] += a0 * w.y; acc[0][2] += a0 * w.z; acc[0][3] += a0 * w.w;
    acc[1][0] += a1 * w.x; acc[1][1] += a1 * w.y; acc[1][2] += a1 * w.z; acc[1][3] += a1 * w.w;
  }
  #pragma unroll
  for (int mi = 0; mi < 2; ++mi) {
    size_t o = (size_t)(m0 + tm * 2 + mi) * 768 + n0 + tn * 4;
    float4 r = *(float4*)&h[o];
    r.x += acc[mi][0]; r.y += acc[mi][1]; r.z += acc[mi][2]; r.w += acc[mi][3];
    *(float4*)&h[o] = r;
  }
}

// ---------------- K7: LayerNorm -> bf16 ----------------
__global__ __launch_bounds__(256) void ln_bf16(const float* __restrict__ h,
                                               const float* __restrict__ gamma,
                                               const float* __restrict__ beta,
                                               unsigned short* __restrict__ hnb) {
  __shared__ float red[10];
  int m = blockIdx.x;
  const float* row = h + (size_t)m * 768;
  int tid = threadIdx.x;
  float a0 = row[tid], a1 = row[tid + 256], a2 = row[tid + 512];
  float s = a0 + a1 + a2;
  float s2 = a0 * a0 + a1 * a1 + a2 * a2;
  #pragma unroll
  for (int o = 32; o > 0; o >>= 1) { s += __shfl_down(s, o); s2 += __shfl_down(s2, o); }
  int wv = tid >> 6;
  if ((tid & 63) == 0) { red[wv] = s; red[4 + wv] = s2; }
  __syncthreads();
  if (tid == 0) {
    float S = red[0] + red[1] + red[2] + red[3];
    float S2 = red[4] + red[5] + red[6] + red[7];
    float mu = S * (1.f / 768.f);
    float var = S2 * (1.f / 768.f) - mu * mu;
    red[8] = mu;
    red[9] = rsqrtf(var + 1e-5f);
  }
  __syncthreads();
  float mu = red[8], rs = red[9];
  unsigned short* orow = hnb + (size_t)m * 768;
  orow[tid]       = f32_to_bf16((a0 - mu) * rs * gamma[tid]       + beta[tid]);
  orow[tid + 256] = f32_to_bf16((a1 - mu) * rs * gamma[tid + 256] + beta[tid + 256]);
  orow[tid + 512] = f32_to_bf16((a2 - mu) * rs * gamma[tid + 512] + beta[tid + 512]);
}

// ---------------- K8: tied head GEMM, m97 recipe ----------------
// C[2048][50257] = Hn[2048][768](bf16) x Eb[v][768](bf16, B^T layout)
// 128x128 tile, BK=64, global_load_lds x16B, 4 waves each 64x64 (4x4 MFMA 16x16x32)
__global__ __launch_bounds__(256) void gemm_head(const unsigned short* __restrict__ Hnb,
                                                 const unsigned short* __restrict__ Eb,
                                                 float* __restrict__ out) {
  __shared__ unsigned short As[128 * 64];
  __shared__ unsigned short Bs[128 * 64];
  const int m0 = blockIdx.x * 128;
  const int v0 = blockIdx.y * 128;
  const int tid = threadIdx.x;
  const int lane = tid & 63;
  const int wave = tid >> 6;
  const int wm = (wave & 1) * 64;
  const int wn = (wave >> 1) * 64;
  const int lrow = lane >> 3;          // 0..7
  const int lcol = (lane & 7) * 8;     // element col 0..56

  f32x4 acc[4][4];
  #pragma unroll
  for (int i = 0; i < 4; ++i)
    #pragma unroll
    for (int j = 0; j < 4; ++j)
      acc[i][j] = f32x4{0.f, 0.f, 0.f, 0.f};

  for (int k0 = 0; k0 < 768; k0 += 64) {
    #pragma unroll
    for (int inst = 0; inst < 4; ++inst) {
      int c = wave * 4 + inst;         // chunk 0..15, 1 KiB each
      int r = c * 8 + lrow;            // tile row 0..127
      gload_lds16(Hnb + (size_t)(m0 + r) * 768 + k0 + lcol, &As[c * 512]);
      gload_lds16(Eb  + (size_t)(v0 + r) * 768 + k0 + lcol, &Bs[c * 512]);
    }
    __syncthreads();   // drains vmcnt for global_load_lds then barriers
    #pragma unroll
    for (int kk = 0; kk < 64; kk += 32) {
      bf16x8 af[4], bfr[4];
      int row_a = wm + (lane & 15);
      int row_b = wn + (lane & 15);
      int coloff = ((lane >> 4) * 8) + kk;
      #pragma unroll
      for (int i = 0; i < 4; ++i)
        af[i] = *(const bf16x8*)(&As[(row_a + i * 16) * 64 + coloff]);
      #pragma unroll
      for (int j = 0; j < 4; ++j)
        bfr[j] = *(const bf16x8*)(&Bs[(row_b + j * 16) * 64 + coloff]);
      #pragma unroll
      for (int i = 0; i < 4; ++i)
        #pragma unroll
        for (int j = 0; j < 4; ++j)
          acc[i][j] = __builtin_amdgcn_mfma_f32_16x16x32_bf16(af[i], bfr[j], acc[i][j], 0, 0, 0);
    }
    __syncthreads();
  }

  const int cr = (lane >> 4) * 4;   // C/D: col = lane&15, row = (lane>>4)*4 + reg
  const int cc = lane & 15;
  #pragma unroll
  for (int i = 0; i < 4; ++i) {
    #pragma unroll
    for (int j = 0; j < 4; ++j) {
      int gc = v0 + wn + j * 16 + cc;
      if (gc < VSZ) {
        size_t base = (size_t)(m0 + wm + i * 16 + cr) * VSZ + gc;
        #pragma unroll
        for (int r = 0; r < 4; ++r)
          out[base + (size_t)r * VSZ] = acc[i][j][r];
      }
    }
  }
}

// ---------------- launch ----------------
extern "C" void kernel_launch(void* const* d_in, const int* in_sizes, int n_in,
                              void* d_out, int out_size, void* d_ws, size_t ws_size,
                              hipStream_t stream) {
  (void)in_sizes; (void)n_in; (void)out_size; (void)ws_size;
  const int*   x       = (const int*)d_in[0];
  const float* embed   = (const float*)d_in[1];
  const float* conv_w  = (const float*)d_in[2];
  const float* conv_b  = (const float*)d_in[3];
  const float* W_delta = (const float*)d_in[4];
  const float* b_delta = (const float*)d_in[5];
  const float* W_in    = (const float*)d_in[6];
  const float* W_out   = (const float*)d_in[7];
  const float* log_A   = (const float*)d_in[8];
  const float* gamma   = (const float*)d_in[9];
  const float* beta    = (const float*)d_in[10];
  float* out = (float*)d_out;

  char* wsp = (char*)d_ws;
  size_t off = 0;
  auto carve = [&](size_t bytes) -> char* {
    char* p = wsp + off;
    off += (bytes + 255) & ~(size_t)255;
    return p;
  };
  unsigned short* Eb  = (unsigned short*)carve((size_t)VPAD * 768 * 2);  // 77.3 MB
  float* h            = (float*)carve((size_t)BL_ * 768 * 4);
  float* u            = (float*)carve((size_t)BL_ * 768 * 4);
  float* pre          = (float*)carve((size_t)BL_ * 256 * 4);
  float* hsbuf        = (float*)carve((size_t)BL_ * 128 * 4);
  float* cP           = (float*)carve(32 * 256 * 4);
  float* cQ           = (float*)carve(32 * 256 * 4);
  float* sst          = (float*)carve(32 * 256 * 4);
  unsigned short* hnb = (unsigned short*)carve((size_t)BL_ * 768 * 2);

  convert_embed<<<(VPAD * 192) / 256, 256, 0, stream>>>(embed, Eb);
  gather_embed<<<(BL_ * 192) / 256, 256, 0, stream>>>(x, embed, h);

  for (int i = 0; i < 4; ++i) {
    conv_silu<<<(BL_ * 192) / 256, 256, 0, stream>>>(h, conv_w + (size_t)i * 768 * 4,
                                                     conv_b + (size_t)i * 768, u);
    gemm_dbu<<<dim3(128, 2), 256, 0, stream>>>(u, W_delta + (size_t)i * 768 * 128,
                                               W_in + (size_t)i * 768 * 128, pre);
    scan_chunks<<<32, 256, 0, stream>>>(pre, b_delta + i * 128, log_A + i * 128, cP, cQ);
    scan_tops<<<1, 256, 0, stream>>>(cP, cQ, sst);
    scan_final<<<32, 256, 0, stream>>>(pre, b_delta + i * 128, log_A + i * 128, sst, hsbuf);
    gemm_out<<<dim3(128, 6), 256, 0, stream>>>(hsbuf, W_out + (size_t)i * 128 * 768, h);
  }

  ln_bf16<<<BL_, 256, 0, stream>>>(h, gamma, beta, hnb);
  gemm_head<<<dim3(16, 393), 256, 0, stream>>>(hnb, Eb, out);
}